// Round 2
// baseline (1040.145 us; speedup 1.0000x reference)
//
#include <hip/hip_runtime.h>

// Problem constants
#define NC   8192
#define NEFF 8192
#define DIN  256
#define DOUT 128
#define SCALE 0.08838834764831843f  // 1/sqrt(128)

typedef float  f32x4  __attribute__((ext_vector_type(4)));
typedef short  s16x8  __attribute__((ext_vector_type(8)));
typedef unsigned long long u64;

// RNE float -> bf16 (as short)
__device__ __forceinline__ short f2bf(float f) {
    unsigned int u = __builtin_bit_cast(unsigned int, f);
    u += 0x7FFFu + ((u >> 16) & 1u);
    return (short)(u >> 16);
}

__device__ __forceinline__ s16x8 ld8(const short* p) {
    return *(const s16x8*)__builtin_assume_aligned(p, 16);
}

// ---------------------------------------------------------------------------
// Kernel 0: pack mask (268 MB int32) -> row-major bitmap (8 MB).
// bm[row*128 + g] bit j  <=>  mask[row*8192 + g*64 + j] != 0.
// Lane-per-int coalesced read + __ballot. BW-bound.
// ---------------------------------------------------------------------------
__global__ __launch_bounds__(256) void pack_kernel(
    const int* __restrict__ mask, u64* __restrict__ bm)
{
    const size_t stride = (size_t)gridDim.x * 256;     // multiple of 64
    const size_t i0 = (size_t)blockIdx.x * 256 + threadIdx.x;
    const bool lead = (threadIdx.x & 63) == 0;
    // 8192*8192 ints / (stride*4) iterations, 4 independent loads per pass
    for (size_t i = i0; i < (size_t)NC * NEFF; i += 4 * stride) {
        const int m0 = mask[i];
        const int m1 = mask[i + stride];
        const int m2 = mask[i + 2 * stride];
        const int m3 = mask[i + 3 * stride];
        const u64 b0 = __ballot(m0 != 0);
        const u64 b1 = __ballot(m1 != 0);
        const u64 b2 = __ballot(m2 != 0);
        const u64 b3 = __ballot(m3 != 0);
        if (lead) {
            bm[i >> 6] = b0;
            bm[(i + stride) >> 6] = b1;
            bm[(i + 2 * stride) >> 6] = b2;
            bm[(i + 3 * stride) >> 6] = b3;
        }
    }
}

// ---------------------------------------------------------------------------
// Kernel 1: QKV projections.  grid(128, 3): blockIdx.x = 64-row block,
// blockIdx.y = matrix (0=Q scaled, 1=K, 2=V transposed).
// ---------------------------------------------------------------------------
__global__ __launch_bounds__(256, 2) void qkv_kernel(
    const float* __restrict__ embc, const float* __restrict__ embe,
    const float* __restrict__ Wq, const float* __restrict__ bq,
    const float* __restrict__ Wk, const float* __restrict__ bk,
    const float* __restrict__ Wv, const float* __restrict__ bv,
    short* __restrict__ Qs, short* __restrict__ Kb, short* __restrict__ Vt)
{
    const int mat = blockIdx.y;
    const float* src  = (mat == 0) ? embc : embe;
    const float* W    = (mat == 0) ? Wq : (mat == 1 ? Wk : Wv);
    const float* bias = (mat == 0) ? bq : (mat == 1 ? bk : bv);

    __shared__ short wt[DOUT][136];
    __shared__ short vbuf[DOUT][72];   // V transpose staging (mat==2 only)

    const int tid  = threadIdx.x;
    const int wave = tid >> 6, lane = tid & 63;
    const int quad = lane >> 4, ln16 = lane & 15;
    const int rowbase = blockIdx.x * 64;
    const int arow = rowbase + wave * 16 + ln16;   // A-fragment row

    f32x4 acc[8];
#pragma unroll
    for (int i = 0; i < 8; i++) acc[i] = (f32x4){0.f, 0.f, 0.f, 0.f};

    for (int h = 0; h < 2; h++) {
        __syncthreads();   // WAR vs previous half's reads
        {   // stage W[h*128 .. +127][0..127] transposed into wt (bf16)
            const int n0 = (tid & 31) * 4;
            const int kb = tid >> 5;               // 0..7
#pragma unroll
            for (int i = 0; i < 16; i++) {
                const int k = kb + i * 8;          // 0..127 (local)
                const float4 w4 = *(const float4*)(W + (size_t)(h * 128 + k) * DOUT + n0);
                wt[n0 + 0][k] = f2bf(w4.x);
                wt[n0 + 1][k] = f2bf(w4.y);
                wt[n0 + 2][k] = f2bf(w4.z);
                wt[n0 + 3][k] = f2bf(w4.w);
            }
        }
        __syncthreads();

        s16x8 afr[4];
#pragma unroll
        for (int kc = 0; kc < 4; kc++) {
            const float* ap = src + (size_t)arow * DIN + h * 128 + kc * 32 + quad * 8;
            const float4 a0 = *(const float4*)ap;
            const float4 a1 = *(const float4*)(ap + 4);
            s16x8 a;
            a[0] = f2bf(a0.x); a[1] = f2bf(a0.y); a[2] = f2bf(a0.z); a[3] = f2bf(a0.w);
            a[4] = f2bf(a1.x); a[5] = f2bf(a1.y); a[6] = f2bf(a1.z); a[7] = f2bf(a1.w);
            afr[kc] = a;
        }
#pragma unroll
        for (int nt = 0; nt < 8; nt++) {
#pragma unroll
            for (int kc = 0; kc < 4; kc++) {
                const s16x8 b = ld8(&wt[nt * 16 + ln16][kc * 32 + quad * 8]);
                acc[nt] = __builtin_amdgcn_mfma_f32_16x16x32_bf16(afr[kc], b, acc[nt], 0, 0, 0);
            }
        }
    }

    if (mat < 2) {
        short* dst = (mat == 0) ? Qs : Kb;
        const float sc = (mat == 0) ? SCALE : 1.0f;
#pragma unroll
        for (int nt = 0; nt < 8; nt++) {
            const int col = nt * 16 + ln16;
            const float bb = bias[col];
#pragma unroll
            for (int r = 0; r < 4; r++) {
                const int row = rowbase + wave * 16 + quad * 4 + r;
                dst[(size_t)row * DOUT + col] = f2bf((acc[nt][r] + bb) * sc);
            }
        }
    } else {
        __syncthreads();
#pragma unroll
        for (int nt = 0; nt < 8; nt++) {
            const int col = nt * 16 + ln16;
            const float bb = bias[col];
#pragma unroll
            for (int r = 0; r < 4; r++) {
                const int row = wave * 16 + quad * 4 + r;   // within 64-row block
                vbuf[col][row] = f2bf(acc[nt][r] + bb);
            }
        }
        __syncthreads();
        const int col = tid >> 1, half = tid & 1;
        short* gp = Vt + (size_t)col * NC + rowbase + half * 32;
        const short* lp = &vbuf[col][half * 32];
#pragma unroll
        for (int i = 0; i < 4; i++)
            *(s16x8*)(gp + i * 8) = ld8(lp + i * 8);
    }
}

// ---------------------------------------------------------------------------
// Kernel 2: per-row sum of exp(masked scores), reading the 8 MB bitmap.
// grid(256, 8): blockIdx.x = 32-row block, blockIdx.y = 1024-col strip.
// Wave w: rows 16*(w&1), cols 64*(w>>1) within each 128-col tile.
// ---------------------------------------------------------------------------
__global__ __launch_bounds__(256, 8) void stats_kernel(
    const u64* __restrict__ bm, const short* __restrict__ Qs,
    const short* __restrict__ Kb, float* __restrict__ lsum)
{
    const int rb = blockIdx.x, strip = blockIdx.y;
    const int tid  = threadIdx.x;
    const int wave = tid >> 6, lane = tid & 63;
    const int quad = lane >> 4, ln16 = lane & 15;
    const int rowbase = rb * 32 + (wave & 1) * 16;
    const int wcol = (wave >> 1) * 64;

    s16x8 aq[4];
#pragma unroll
    for (int kc = 0; kc < 4; kc++)
        aq[kc] = ld8(Qs + (size_t)(rowbase + ln16) * DOUT + kc * 32 + quad * 8);

    float lp[4] = {0.f, 0.f, 0.f, 0.f};

    for (int ct = 0; ct < 8; ct++) {
        const int colbase = strip * 1024 + ct * 128 + wcol;
        f32x4 c[4];
#pragma unroll
        for (int nt = 0; nt < 4; nt++) c[nt] = (f32x4){0.f, 0.f, 0.f, 0.f};
#pragma unroll
        for (int nt = 0; nt < 4; nt++)
#pragma unroll
            for (int kc = 0; kc < 4; kc++) {
                const s16x8 b = ld8(Kb + (size_t)(colbase + nt * 16 + ln16) * DOUT + kc * 32 + quad * 8);
                c[nt] = __builtin_amdgcn_mfma_f32_16x16x32_bf16(aq[kc], b, c[nt], 0, 0, 0);
            }

        const int g = colbase >> 6;
#pragma unroll
        for (int r = 0; r < 4; r++) {
            const int row = rowbase + quad * 4 + r;
            const u64 bits = bm[(size_t)row * 128 + g] >> ln16;
#pragma unroll
            for (int nt = 0; nt < 4; nt++) {
                if ((bits >> (nt * 16)) & 1ull) lp[r] += __expf(c[nt][r]);
            }
        }
    }

#pragma unroll
    for (int r = 0; r < 4; r++) {
        float v = lp[r];
        v += __shfl_xor(v, 1); v += __shfl_xor(v, 2);
        v += __shfl_xor(v, 4); v += __shfl_xor(v, 8);
        if (ln16 == 0) atomicAdd(&lsum[rowbase + quad * 4 + r], v);
    }
}

// ---------------------------------------------------------------------------
// Kernel 3: recompute S, write normalized weights, fused O = W @ V.
// grid(256, 4). No block barriers in the ct loop: wlds is PER-WAVE, so only
// a wave-internal lgkmcnt drain is needed (DS pipe is in-order per wave).
// ---------------------------------------------------------------------------
__global__ __launch_bounds__(256, 4) void attn_kernel(
    const short* __restrict__ Qs, const short* __restrict__ Kb,
    const short* __restrict__ Vt, const float* __restrict__ lsum,
    const u64* __restrict__ bm,
    float* __restrict__ outO, float* __restrict__ outW)
{
    __shared__ short wlds[4][16][72];   // per-wave W tile (16 rows x 64 cols)
    __shared__ float obuf[32][132];     // O merge buffer

    const int rb = blockIdx.x, strip = blockIdx.y;
    const int tid  = threadIdx.x;
    const int wave = tid >> 6, lane = tid & 63;
    const int quad = lane >> 4, ln16 = lane & 15;
    const int rowbase = rb * 32 + (wave & 1) * 16;
    const int wcol = (wave >> 1) * 64;

    s16x8 aq[4];
#pragma unroll
    for (int kc = 0; kc < 4; kc++)
        aq[kc] = ld8(Qs + (size_t)(rowbase + ln16) * DOUT + kc * 32 + quad * 8);

    float rl[4];
#pragma unroll
    for (int r = 0; r < 4; r++)
        rl[r] = 1.0f / lsum[rowbase + quad * 4 + r];

    f32x4 o[8];
#pragma unroll
    for (int i = 0; i < 8; i++) o[i] = (f32x4){0.f, 0.f, 0.f, 0.f};

    for (int ct = 0; ct < 16; ct++) {
        const int colbase = strip * 2048 + ct * 128 + wcol;
        f32x4 c[4];
#pragma unroll
        for (int nt = 0; nt < 4; nt++) c[nt] = (f32x4){0.f, 0.f, 0.f, 0.f};
#pragma unroll
        for (int nt = 0; nt < 4; nt++)
#pragma unroll
            for (int kc = 0; kc < 4; kc++) {
                const s16x8 b = ld8(Kb + (size_t)(colbase + nt * 16 + ln16) * DOUT + kc * 32 + quad * 8);
                c[nt] = __builtin_amdgcn_mfma_f32_16x16x32_bf16(aq[kc], b, c[nt], 0, 0, 0);
            }

        const int g = colbase >> 6;
#pragma unroll
        for (int r = 0; r < 4; r++) {
            const int row = rowbase + quad * 4 + r;
            const u64 bits = bm[(size_t)row * 128 + g] >> ln16;
            float* wrow = outW + (size_t)row * NEFF + colbase + ln16;
#pragma unroll
            for (int nt = 0; nt < 4; nt++) {
                const float w = ((bits >> (nt * 16)) & 1ull) ? __expf(c[nt][r]) * rl[r] : 0.0f;
                wrow[nt * 16] = w;
                wlds[wave][quad * 4 + r][nt * 16 + ln16] = f2bf(w);
            }
        }
        // wave-internal: drain this wave's ds_writes before its ds_reads.
        asm volatile("s_waitcnt lgkmcnt(0)" ::: "memory");
        const s16x8 aw0 = ld8(&wlds[wave][ln16][quad * 8]);
        const s16x8 aw1 = ld8(&wlds[wave][ln16][32 + quad * 8]);
#pragma unroll
        for (int nt2 = 0; nt2 < 8; nt2++) {
            const short* vrow = Vt + (size_t)(nt2 * 16 + ln16) * NC + colbase;
            const s16x8 b0 = ld8(vrow + quad * 8);
            const s16x8 b1 = ld8(vrow + 32 + quad * 8);
            o[nt2] = __builtin_amdgcn_mfma_f32_16x16x32_bf16(aw0, b0, o[nt2], 0, 0, 0);
            o[nt2] = __builtin_amdgcn_mfma_f32_16x16x32_bf16(aw1, b1, o[nt2], 0, 0, 0);
        }
        // compiler fence: keep next iteration's ds_writes after the ds_reads
        asm volatile("" ::: "memory");
    }

    // merge partial O across wave pairs (0,2) and (1,3) via LDS
    if (wave < 2) {
#pragma unroll
        for (int nt2 = 0; nt2 < 8; nt2++)
#pragma unroll
            for (int r = 0; r < 4; r++)
                obuf[(wave & 1) * 16 + quad * 4 + r][nt2 * 16 + ln16] = o[nt2][r];
    }
    __syncthreads();
    if (wave >= 2) {
#pragma unroll
        for (int nt2 = 0; nt2 < 8; nt2++)
#pragma unroll
            for (int r = 0; r < 4; r++)
                obuf[(wave & 1) * 16 + quad * 4 + r][nt2 * 16 + ln16] += o[nt2][r];
    }
    __syncthreads();
    // strip-partial O -> global via f32 atomics (outO pre-zeroed)
#pragma unroll
    for (int i = 0; i < 16; i++) {
        const int idx = tid + i * 256;          // 0..4095
        const int row = idx >> 7, colf = idx & 127;
        atomicAdd(&outO[(size_t)(rb * 32 + row) * DOUT + colf], obuf[row][colf]);
    }
}

// ---------------------------------------------------------------------------
extern "C" void kernel_launch(void* const* d_in, const int* in_sizes, int n_in,
                              void* d_out, int out_size, void* d_ws, size_t ws_size,
                              hipStream_t stream) {
    (void)in_sizes; (void)n_in; (void)out_size; (void)ws_size;

    const float* embc = (const float*)d_in[0];
    const float* embe = (const float*)d_in[1];
    const int*   mask = (const int*)d_in[2];
    const float* Wq = (const float*)d_in[3];
    const float* bq = (const float*)d_in[4];
    const float* Wk = (const float*)d_in[5];
    const float* bk = (const float*)d_in[6];
    const float* Wv = (const float*)d_in[7];
    const float* bv = (const float*)d_in[8];

    char* ws = (char*)d_ws;
    short* Qs = (short*)(ws);                        // 2 MB  (bf16, pre-scaled)
    short* Kb = (short*)(ws + (2u << 20));           // 2 MB
    short* Vt = (short*)(ws + (4u << 20));           // 2 MB  (transposed [feat][col])
    float* lsum = (float*)(ws + (6u << 20));         // 32 KB
    u64*   bm  = (u64*)(ws + (8u << 20));            // 8 MB row-major bitmap

    float* outO = (float*)d_out;                     // [8192,128]
    float* outW = outO + (size_t)NC * DOUT;          // [8192,8192]

    hipMemsetAsync(lsum, 0, NC * sizeof(float), stream);
    hipMemsetAsync(outO, 0, (size_t)NC * DOUT * sizeof(float), stream);

    pack_kernel<<<16384, 256, 0, stream>>>(mask, bm);
    qkv_kernel<<<dim3(128, 3), 256, 0, stream>>>(embc, embe, Wq, bq, Wk, bk, Wv, bv,
                                                 Qs, Kb, Vt);
    stats_kernel<<<dim3(256, 8), 256, 0, stream>>>(bm, Qs, Kb, lsum);
    attn_kernel<<<dim3(256, 4), 256, 0, stream>>>(Qs, Kb, Vt, lsum, bm, outO, outW);
}

// Round 3
// 728.067 us; speedup vs baseline: 1.4286x; 1.4286x over previous
//
#include <hip/hip_runtime.h>

// Problem constants
#define NC   8192
#define NEFF 8192
#define DIN  256
#define DOUT 128
#define SCALE 0.08838834764831843f  // 1/sqrt(128)

typedef float  f32x4  __attribute__((ext_vector_type(4)));
typedef short  s16x8  __attribute__((ext_vector_type(8)));
typedef unsigned long long u64;

// RNE float -> bf16 (as short)
__device__ __forceinline__ short f2bf(float f) {
    unsigned int u = __builtin_bit_cast(unsigned int, f);
    u += 0x7FFFu + ((u >> 16) & 1u);
    return (short)(u >> 16);
}

__device__ __forceinline__ s16x8 ld8(const short* p) {
    return *(const s16x8*)__builtin_assume_aligned(p, 16);
}

__device__ __forceinline__ unsigned getdw(int4 v, int i) {
    switch (i & 3) {
        case 0: return (unsigned)v.x;
        case 1: return (unsigned)v.y;
        case 2: return (unsigned)v.z;
        default: return (unsigned)v.w;
    }
}

// ---------------------------------------------------------------------------
// Fragment-major layouts (all bf16, s16x8 = one lane's A/B fragment):
//  Qf[tile(512)][kc(4)][lane(64)] : Q[tile*16+ln16][kc*32+quad*8+j] * SCALE
//  Kf[tile(512)][kc(4)][lane(64)] : K[tile*16+ln16][kc*32+quad*8+j]
//  Vf[ct(64)][nt2(8)][ksub(4)][lane(64)] : V[ct*128+ksub*32+quad*8+j][nt2*16+ln16]
// A wave's fragment load is base + lane*16B -> perfectly coalesced 1KB stream.
// ---------------------------------------------------------------------------

// ---------------------------------------------------------------------------
// Kernel 1: QKV projections. grid(128, 3): blockIdx.x = 64-row block,
// blockIdx.y = matrix (0=Qf scaled, 1=Kf, 2=Vf).
// ---------------------------------------------------------------------------
__global__ __launch_bounds__(256, 2) void qkv_kernel(
    const float* __restrict__ embc, const float* __restrict__ embe,
    const float* __restrict__ Wq, const float* __restrict__ bq,
    const float* __restrict__ Wk, const float* __restrict__ bk,
    const float* __restrict__ Wv, const float* __restrict__ bv,
    short* __restrict__ Qf, short* __restrict__ Kf, short* __restrict__ Vf)
{
    const int mat = blockIdx.y;
    const float* src  = (mat == 0) ? embc : embe;
    const float* W    = (mat == 0) ? Wq : (mat == 1 ? Wk : Wv);
    const float* bias = (mat == 0) ? bq : (mat == 1 ? bk : bv);

    __shared__ short wt[DOUT][136];       // W^T staging (half-K at a time)
    __shared__ short tbuf[4][16][132];    // per-wave transpose buffer (Q/K path)
    __shared__ short tbufV[128][68];      // block-wide transpose buffer (V path)

    const int tid  = threadIdx.x;
    const int wave = tid >> 6, lane = tid & 63;
    const int quad = lane >> 4, ln16 = lane & 15;
    const int rowbase = blockIdx.x * 64;
    const int arow = rowbase + wave * 16 + ln16;   // A-fragment row

    f32x4 acc[8];
#pragma unroll
    for (int i = 0; i < 8; i++) acc[i] = (f32x4){0.f, 0.f, 0.f, 0.f};

    for (int h = 0; h < 2; h++) {
        __syncthreads();   // WAR vs previous half's reads
        {   // stage W[h*128 .. +127][0..127] transposed into wt (bf16)
            const int n0 = (tid & 31) * 4;
            const int kb = tid >> 5;               // 0..7
#pragma unroll
            for (int i = 0; i < 16; i++) {
                const int k = kb + i * 8;          // 0..127 (local)
                const float4 w4 = *(const float4*)(W + (size_t)(h * 128 + k) * DOUT + n0);
                wt[n0 + 0][k] = f2bf(w4.x);
                wt[n0 + 1][k] = f2bf(w4.y);
                wt[n0 + 2][k] = f2bf(w4.z);
                wt[n0 + 3][k] = f2bf(w4.w);
            }
        }
        __syncthreads();

        s16x8 afr[4];
#pragma unroll
        for (int kc = 0; kc < 4; kc++) {
            const float* ap = src + (size_t)arow * DIN + h * 128 + kc * 32 + quad * 8;
            const float4 a0 = *(const float4*)ap;
            const float4 a1 = *(const float4*)(ap + 4);
            s16x8 a;
            a[0] = f2bf(a0.x); a[1] = f2bf(a0.y); a[2] = f2bf(a0.z); a[3] = f2bf(a0.w);
            a[4] = f2bf(a1.x); a[5] = f2bf(a1.y); a[6] = f2bf(a1.z); a[7] = f2bf(a1.w);
            afr[kc] = a;
        }
#pragma unroll
        for (int nt = 0; nt < 8; nt++) {
#pragma unroll
            for (int kc = 0; kc < 4; kc++) {
                const s16x8 b = ld8(&wt[nt * 16 + ln16][kc * 32 + quad * 8]);
                acc[nt] = __builtin_amdgcn_mfma_f32_16x16x32_bf16(afr[kc], b, acc[nt], 0, 0, 0);
            }
        }
    }

    if (mat < 2) {
        short* dst = (mat == 0) ? Qf : Kf;
        const float sc = (mat == 0) ? SCALE : 1.0f;
        // C-layout -> tbuf (per-wave; wave-internal ordering only)
#pragma unroll
        for (int nt = 0; nt < 8; nt++) {
            const float bb = bias[nt * 16 + ln16];
#pragma unroll
            for (int r = 0; r < 4; r++)
                tbuf[wave][quad * 4 + r][nt * 16 + ln16] = f2bf((acc[nt][r] + bb) * sc);
        }
        const int tile = blockIdx.x * 4 + wave;
#pragma unroll
        for (int kc = 0; kc < 4; kc++) {
            const s16x8 fr = ld8(&tbuf[wave][ln16][kc * 32 + quad * 8]);
            *(s16x8*)(dst + ((size_t)(tile * 4 + kc) * 64 + lane) * 8) = fr;
        }
    } else {
        // V: transpose to [feat][vcol] then emit PV B-fragments
#pragma unroll
        for (int nt = 0; nt < 8; nt++) {
            const float bb = bias[nt * 16 + ln16];
#pragma unroll
            for (int r = 0; r < 4; r++)
                tbufV[nt * 16 + ln16][wave * 16 + quad * 4 + r] = f2bf(acc[nt][r] + bb);
        }
        __syncthreads();   // cross-wave reads of tbufV
        const int ct = blockIdx.x >> 1;
        const int ksub0 = (blockIdx.x & 1) * 2;
        const int ks = wave & 1;
#pragma unroll
        for (int t = 0; t < 4; t++) {
            const int nt2 = (wave >> 1) * 4 + t;
            const s16x8 fr = ld8(&tbufV[nt2 * 16 + ln16][ks * 32 + quad * 8]);
            *(s16x8*)(Vf + ((size_t)((ct * 8 + nt2) * 4 + ksub0 + ks) * 64 + lane) * 8) = fr;
        }
    }
}

// ---------------------------------------------------------------------------
// Kernel 2: mask pack (268MB -> 8MB bm) + per-row sum of exp(masked scores).
// grid(64, 8): blockIdx.x = 128-row block, blockIdx.y = 1024-col strip.
// Wave w owns rows bx*128 + w*32 .. +32.  Mask read is coalesced lane-per-col
// + __ballot; bits round-trip through LDS to reach MFMA C-layout lanes.
// bm dword layout: bm[row*256 + col/32], bit = col%32 within each 32-col dword
// grouped as int4 per 128 cols (dword idx nt>>1, shift (nt&1)*16+ln16).
// ---------------------------------------------------------------------------
__global__ __launch_bounds__(256, 2) void stats_kernel(
    const int* __restrict__ mask, const short* __restrict__ Qf,
    const short* __restrict__ Kf, float* __restrict__ lsum,
    unsigned int* __restrict__ bm)
{
    __shared__ int4 bmbuf[4][32];

    const int bx = blockIdx.x, strip = blockIdx.y;
    const int tid  = threadIdx.x;
    const int wave = tid >> 6, lane = tid & 63;
    const int quad = lane >> 4, ln16 = lane & 15;
    const int rowbase = bx * 128 + wave * 32;
    const int t0 = rowbase >> 4;

    s16x8 aq[2][4];
#pragma unroll
    for (int rs = 0; rs < 2; rs++)
#pragma unroll
        for (int kc = 0; kc < 4; kc++)
            aq[rs][kc] = ld8(Qf + ((size_t)((t0 + rs) * 4 + kc) * 64 + lane) * 8);

    float lp[8] = {0.f, 0.f, 0.f, 0.f, 0.f, 0.f, 0.f, 0.f};

    for (int it = 0; it < 8; it++) {
        const int cb = strip * 1024 + it * 128;

        // --- coalesced mask read + ballot pack ---
        int4 mybm = {0, 0, 0, 0};
#pragma unroll 4
        for (int rr = 0; rr < 32; rr++) {
            const int* mrow = mask + (size_t)(rowbase + rr) * NEFF + cb;
            const int p0 = mrow[lane];
            const int p1 = mrow[64 + lane];
            const u64 b0 = __ballot(p0 != 0);
            const u64 b1 = __ballot(p1 != 0);
            int4 v;
            v.x = (int)(unsigned)(b0 & 0xffffffffull);
            v.y = (int)(unsigned)(b0 >> 32);
            v.z = (int)(unsigned)(b1 & 0xffffffffull);
            v.w = (int)(unsigned)(b1 >> 32);
            if (rr == lane) mybm = v;
        }
        if (lane < 32) {
            *(int4*)(bm + (size_t)(rowbase + lane) * 256 + (cb >> 5)) = mybm;
            bmbuf[wave][lane] = mybm;
        }
        int4 bmv[2][4];
#pragma unroll
        for (int rs = 0; rs < 2; rs++)
#pragma unroll
            for (int r = 0; r < 4; r++)
                bmv[rs][r] = bmbuf[wave][rs * 16 + quad * 4 + r];

        // --- QK^T + masked exp accumulate ---
#pragma unroll
        for (int nt = 0; nt < 8; nt++) {
            s16x8 bq[4];
#pragma unroll
            for (int kc = 0; kc < 4; kc++)
                bq[kc] = ld8(Kf + ((size_t)(((cb >> 4) + nt) * 4 + kc) * 64 + lane) * 8);
            f32x4 c0 = (f32x4){0.f, 0.f, 0.f, 0.f};
            f32x4 c1 = (f32x4){0.f, 0.f, 0.f, 0.f};
#pragma unroll
            for (int kc = 0; kc < 4; kc++) {
                c0 = __builtin_amdgcn_mfma_f32_16x16x32_bf16(aq[0][kc], bq[kc], c0, 0, 0, 0);
                c1 = __builtin_amdgcn_mfma_f32_16x16x32_bf16(aq[1][kc], bq[kc], c1, 0, 0, 0);
            }
#pragma unroll
            for (int rs = 0; rs < 2; rs++)
#pragma unroll
                for (int r = 0; r < 4; r++) {
                    const unsigned d = getdw(bmv[rs][r], nt >> 1);
                    const float cv = rs ? c1[r] : c0[r];
                    if ((d >> ((nt & 1) * 16 + ln16)) & 1u)
                        lp[rs * 4 + r] += __expf(cv);
                }
        }
    }

#pragma unroll
    for (int i = 0; i < 8; i++) {
        float v = lp[i];
        v += __shfl_xor(v, 1); v += __shfl_xor(v, 2);
        v += __shfl_xor(v, 4); v += __shfl_xor(v, 8);
        if (ln16 == 0)
            atomicAdd(&lsum[rowbase + (i >> 2) * 16 + quad * 4 + (i & 3)], v);
    }
}

// ---------------------------------------------------------------------------
// Kernel 3: recompute S from fragments, write W, fused O = W @ V.
// grid(64, 8) like stats. All fragment loads are coalesced streams; W-tile
// round-trips per-wave LDS (C-layout -> A-layout); O strip-partials merge
// via f32 atomics into pre-zeroed outO.
// ---------------------------------------------------------------------------
__global__ __launch_bounds__(256, 2) void attn_kernel(
    const short* __restrict__ Qf, const short* __restrict__ Kf,
    const short* __restrict__ Vf, const float* __restrict__ lsum,
    const unsigned int* __restrict__ bm,
    float* __restrict__ outO, float* __restrict__ outW)
{
    __shared__ short wlds[4][32][132];   // per-wave 32x128 W tile (bf16)

    const int bx = blockIdx.x, strip = blockIdx.y;
    const int tid  = threadIdx.x;
    const int wave = tid >> 6, lane = tid & 63;
    const int quad = lane >> 4, ln16 = lane & 15;
    const int rowbase = bx * 128 + wave * 32;
    const int t0 = rowbase >> 4;

    s16x8 aq[2][4];
#pragma unroll
    for (int rs = 0; rs < 2; rs++)
#pragma unroll
        for (int kc = 0; kc < 4; kc++)
            aq[rs][kc] = ld8(Qf + ((size_t)((t0 + rs) * 4 + kc) * 64 + lane) * 8);

    float rl[2][4];
#pragma unroll
    for (int rs = 0; rs < 2; rs++)
#pragma unroll
        for (int r = 0; r < 4; r++)
            rl[rs][r] = 1.0f / lsum[rowbase + rs * 16 + quad * 4 + r];

    f32x4 o[2][8];
#pragma unroll
    for (int rs = 0; rs < 2; rs++)
#pragma unroll
        for (int i = 0; i < 8; i++) o[rs][i] = (f32x4){0.f, 0.f, 0.f, 0.f};

    for (int it = 0; it < 8; it++) {
        const int cb = strip * 1024 + it * 128;

        int4 bmv[2][4];
#pragma unroll
        for (int rs = 0; rs < 2; rs++)
#pragma unroll
            for (int r = 0; r < 4; r++)
                bmv[rs][r] = *(const int4*)(bm + (size_t)(rowbase + rs * 16 + quad * 4 + r) * 256 + (cb >> 5));

#pragma unroll
        for (int nt = 0; nt < 8; nt++) {
            s16x8 bq[4];
#pragma unroll
            for (int kc = 0; kc < 4; kc++)
                bq[kc] = ld8(Kf + ((size_t)(((cb >> 4) + nt) * 4 + kc) * 64 + lane) * 8);
            f32x4 c0 = (f32x4){0.f, 0.f, 0.f, 0.f};
            f32x4 c1 = (f32x4){0.f, 0.f, 0.f, 0.f};
#pragma unroll
            for (int kc = 0; kc < 4; kc++) {
                c0 = __builtin_amdgcn_mfma_f32_16x16x32_bf16(aq[0][kc], bq[kc], c0, 0, 0, 0);
                c1 = __builtin_amdgcn_mfma_f32_16x16x32_bf16(aq[1][kc], bq[kc], c1, 0, 0, 0);
            }
#pragma unroll
            for (int rs = 0; rs < 2; rs++)
#pragma unroll
                for (int r = 0; r < 4; r++) {
                    const int row = rowbase + rs * 16 + quad * 4 + r;
                    const unsigned d = getdw(bmv[rs][r], nt >> 1);
                    const float cv = rs ? c1[r] : c0[r];
                    const float wv = ((d >> ((nt & 1) * 16 + ln16)) & 1u)
                                         ? __expf(cv) * rl[rs][r] : 0.0f;
                    outW[(size_t)row * NEFF + cb + nt * 16 + ln16] = wv;
                    wlds[wave][rs * 16 + quad * 4 + r][nt * 16 + ln16] = f2bf(wv);
                }
        }

        // PV: A from per-wave LDS (wave-internal ordering), B = Vf stream
#pragma unroll
        for (int ks = 0; ks < 4; ks++) {
            const s16x8 aw0 = ld8(&wlds[wave][ln16][ks * 32 + quad * 8]);
            const s16x8 aw1 = ld8(&wlds[wave][16 + ln16][ks * 32 + quad * 8]);
#pragma unroll
            for (int nt2 = 0; nt2 < 8; nt2++) {
                const s16x8 bv = ld8(Vf + ((size_t)(((cb >> 7) * 8 + nt2) * 4 + ks) * 64 + lane) * 8);
                o[0][nt2] = __builtin_amdgcn_mfma_f32_16x16x32_bf16(aw0, bv, o[0][nt2], 0, 0, 0);
                o[1][nt2] = __builtin_amdgcn_mfma_f32_16x16x32_bf16(aw1, bv, o[1][nt2], 0, 0, 0);
            }
        }
    }

    // O strip-partials -> global atomics (outO pre-zeroed)
#pragma unroll
    for (int rs = 0; rs < 2; rs++)
#pragma unroll
        for (int nt2 = 0; nt2 < 8; nt2++)
#pragma unroll
            for (int r = 0; r < 4; r++) {
                const int row = rowbase + rs * 16 + quad * 4 + r;
                atomicAdd(&outO[(size_t)row * DOUT + nt2 * 16 + ln16], o[rs][nt2][r]);
            }
}

// ---------------------------------------------------------------------------
extern "C" void kernel_launch(void* const* d_in, const int* in_sizes, int n_in,
                              void* d_out, int out_size, void* d_ws, size_t ws_size,
                              hipStream_t stream) {
    (void)in_sizes; (void)n_in; (void)out_size; (void)ws_size;

    const float* embc = (const float*)d_in[0];
    const float* embe = (const float*)d_in[1];
    const int*   mask = (const int*)d_in[2];
    const float* Wq = (const float*)d_in[3];
    const float* bq = (const float*)d_in[4];
    const float* Wk = (const float*)d_in[5];
    const float* bk = (const float*)d_in[6];
    const float* Wv = (const float*)d_in[7];
    const float* bv = (const float*)d_in[8];

    char* ws = (char*)d_ws;
    short* Qf = (short*)(ws);                        // 2 MB  frag-major, pre-scaled
    short* Kf = (short*)(ws + (2u << 20));           // 2 MB  frag-major
    short* Vf = (short*)(ws + (4u << 20));           // 2 MB  frag-major (PV B)
    float* lsum = (float*)(ws + (6u << 20));         // 32 KB
    unsigned int* bm = (unsigned int*)(ws + (8u << 20)); // 8 MB bitmap

    float* outO = (float*)d_out;                     // [8192,128]
    float* outW = outO + (size_t)NC * DOUT;          // [8192,8192]

    hipMemsetAsync(lsum, 0, NC * sizeof(float), stream);
    hipMemsetAsync(outO, 0, (size_t)NC * DOUT * sizeof(float), stream);

    qkv_kernel<<<dim3(128, 3), 256, 0, stream>>>(embc, embe, Wq, bq, Wk, bk, Wv, bv,
                                                 Qf, Kf, Vf);
    stats_kernel<<<dim3(64, 8), 256, 0, stream>>>(mask, Qf, Kf, lsum, bm);
    attn_kernel<<<dim3(64, 8), 256, 0, stream>>>(Qf, Kf, Vf, lsum, bm, outO, outW);
}

// Round 4
// 652.172 us; speedup vs baseline: 1.5949x; 1.1164x over previous
//
#include <hip/hip_runtime.h>

// Problem constants
#define NC   8192
#define NEFF 8192
#define DIN  256
#define DOUT 128
#define SCALE 0.08838834764831843f  // 1/sqrt(128)

typedef float  f32x4  __attribute__((ext_vector_type(4)));
typedef short  s16x8  __attribute__((ext_vector_type(8)));
typedef unsigned long long u64;

// RNE float -> bf16 (as short)
__device__ __forceinline__ short f2bf(float f) {
    unsigned int u = __builtin_bit_cast(unsigned int, f);
    u += 0x7FFFu + ((u >> 16) & 1u);
    return (short)(u >> 16);
}

__device__ __forceinline__ s16x8 ld8(const short* p) {
    return *(const s16x8*)__builtin_assume_aligned(p, 16);
}

__device__ __forceinline__ unsigned getdw(int4 v, int i) {
    switch (i & 3) {
        case 0: return (unsigned)v.x;
        case 1: return (unsigned)v.y;
        case 2: return (unsigned)v.z;
        default: return (unsigned)v.w;
    }
}

// ---------------------------------------------------------------------------
// Fragment-major layouts (all bf16, s16x8 = one lane's A/B fragment):
//  Qf[tile(512)][kc(4)][lane(64)] : Q[tile*16+ln16][kc*32+quad*8+j] * SCALE
//  Kf[tile(512)][kc(4)][lane(64)] : K[tile*16+ln16][kc*32+quad*8+j]
//  Vf[ct(64)][nt2(8)][ksub(4)][lane(64)] : V[ct*128+ksub*32+quad*8+j][nt2*16+ln16]
// bm bit layout: bit c%32 of dword bm32[row*256 + c/32]  <=>  mask[row][c]!=0
// ---------------------------------------------------------------------------

// ---------------------------------------------------------------------------
// Kernel 0: pack mask (268 MB int32) -> 8 MB bitmap. Pure streaming read,
// 8 independent loads in flight per wave, 8192 blocks (huge TLP).
// ---------------------------------------------------------------------------
__global__ __launch_bounds__(256) void pack_kernel(
    const int* __restrict__ mask, u64* __restrict__ bm)
{
    const size_t stride = (size_t)gridDim.x * 256;     // multiple of 64
    const size_t i0 = (size_t)blockIdx.x * 256 + threadIdx.x;
    const bool lead = (threadIdx.x & 63) == 0;
    for (size_t i = i0; i < (size_t)NC * NEFF; i += 8 * stride) {
        int m[8];
#pragma unroll
        for (int j = 0; j < 8; j++) m[j] = mask[i + j * stride];
        u64 b[8];
#pragma unroll
        for (int j = 0; j < 8; j++) b[j] = __ballot(m[j] != 0);
        if (lead) {
#pragma unroll
            for (int j = 0; j < 8; j++) bm[(i + j * stride) >> 6] = b[j];
        }
    }
}

// ---------------------------------------------------------------------------
// Kernel 1: QKV projections. grid(128, 3): blockIdx.x = 64-row block,
// blockIdx.y = matrix (0=Qf scaled, 1=Kf, 2=Vf).
// ---------------------------------------------------------------------------
__global__ __launch_bounds__(256, 2) void qkv_kernel(
    const float* __restrict__ embc, const float* __restrict__ embe,
    const float* __restrict__ Wq, const float* __restrict__ bq,
    const float* __restrict__ Wk, const float* __restrict__ bk,
    const float* __restrict__ Wv, const float* __restrict__ bv,
    short* __restrict__ Qf, short* __restrict__ Kf, short* __restrict__ Vf)
{
    const int mat = blockIdx.y;
    const float* src  = (mat == 0) ? embc : embe;
    const float* W    = (mat == 0) ? Wq : (mat == 1 ? Wk : Wv);
    const float* bias = (mat == 0) ? bq : (mat == 1 ? bk : bv);

    __shared__ short wt[DOUT][136];       // W^T staging (half-K at a time)
    __shared__ short tbuf[4][16][132];    // per-wave transpose buffer (Q/K path)
    __shared__ short tbufV[128][68];      // block-wide transpose buffer (V path)

    const int tid  = threadIdx.x;
    const int wave = tid >> 6, lane = tid & 63;
    const int quad = lane >> 4, ln16 = lane & 15;
    const int rowbase = blockIdx.x * 64;
    const int arow = rowbase + wave * 16 + ln16;   // A-fragment row

    f32x4 acc[8];
#pragma unroll
    for (int i = 0; i < 8; i++) acc[i] = (f32x4){0.f, 0.f, 0.f, 0.f};

    for (int h = 0; h < 2; h++) {
        __syncthreads();   // WAR vs previous half's reads
        {   // stage W[h*128 .. +127][0..127] transposed into wt (bf16)
            const int n0 = (tid & 31) * 4;
            const int kb = tid >> 5;               // 0..7
#pragma unroll
            for (int i = 0; i < 16; i++) {
                const int k = kb + i * 8;          // 0..127 (local)
                const float4 w4 = *(const float4*)(W + (size_t)(h * 128 + k) * DOUT + n0);
                wt[n0 + 0][k] = f2bf(w4.x);
                wt[n0 + 1][k] = f2bf(w4.y);
                wt[n0 + 2][k] = f2bf(w4.z);
                wt[n0 + 3][k] = f2bf(w4.w);
            }
        }
        __syncthreads();

        s16x8 afr[4];
#pragma unroll
        for (int kc = 0; kc < 4; kc++) {
            const float* ap = src + (size_t)arow * DIN + h * 128 + kc * 32 + quad * 8;
            const float4 a0 = *(const float4*)ap;
            const float4 a1 = *(const float4*)(ap + 4);
            s16x8 a;
            a[0] = f2bf(a0.x); a[1] = f2bf(a0.y); a[2] = f2bf(a0.z); a[3] = f2bf(a0.w);
            a[4] = f2bf(a1.x); a[5] = f2bf(a1.y); a[6] = f2bf(a1.z); a[7] = f2bf(a1.w);
            afr[kc] = a;
        }
#pragma unroll
        for (int nt = 0; nt < 8; nt++) {
#pragma unroll
            for (int kc = 0; kc < 4; kc++) {
                const s16x8 b = ld8(&wt[nt * 16 + ln16][kc * 32 + quad * 8]);
                acc[nt] = __builtin_amdgcn_mfma_f32_16x16x32_bf16(afr[kc], b, acc[nt], 0, 0, 0);
            }
        }
    }

    if (mat < 2) {
        short* dst = (mat == 0) ? Qf : Kf;
        const float sc = (mat == 0) ? SCALE : 1.0f;
        // C-layout -> tbuf (per-wave; wave-internal ordering only)
#pragma unroll
        for (int nt = 0; nt < 8; nt++) {
            const float bb = bias[nt * 16 + ln16];
#pragma unroll
            for (int r = 0; r < 4; r++)
                tbuf[wave][quad * 4 + r][nt * 16 + ln16] = f2bf((acc[nt][r] + bb) * sc);
        }
        const int tile = blockIdx.x * 4 + wave;
#pragma unroll
        for (int kc = 0; kc < 4; kc++) {
            const s16x8 fr = ld8(&tbuf[wave][ln16][kc * 32 + quad * 8]);
            *(s16x8*)(dst + ((size_t)(tile * 4 + kc) * 64 + lane) * 8) = fr;
        }
    } else {
        // V: transpose to [feat][vcol] then emit PV B-fragments
#pragma unroll
        for (int nt = 0; nt < 8; nt++) {
            const float bb = bias[nt * 16 + ln16];
#pragma unroll
            for (int r = 0; r < 4; r++)
                tbufV[nt * 16 + ln16][wave * 16 + quad * 4 + r] = f2bf(acc[nt][r] + bb);
        }
        __syncthreads();   // cross-wave reads of tbufV
        const int ct = blockIdx.x >> 1;
        const int ksub0 = (blockIdx.x & 1) * 2;
        const int ks = wave & 1;
#pragma unroll
        for (int t = 0; t < 4; t++) {
            const int nt2 = (wave >> 1) * 4 + t;
            const s16x8 fr = ld8(&tbufV[nt2 * 16 + ln16][ks * 32 + quad * 8]);
            *(s16x8*)(Vf + ((size_t)((ct * 8 + nt2) * 4 + ksub0 + ks) * 64 + lane) * 8) = fr;
        }
    }
}

// ---------------------------------------------------------------------------
// Kernel 2: per-row sum of exp(masked scores) from bitmap + fragments.
// grid(64, 16): blockIdx.x = 128-row block (4 waves x 32 rows),
// blockIdx.y = 512-col strip (4 iters of 128 cols). No LDS.
// ---------------------------------------------------------------------------
__global__ __launch_bounds__(256, 4) void stats_kernel(
    const unsigned int* __restrict__ bm, const short* __restrict__ Qf,
    const short* __restrict__ Kf, float* __restrict__ lsum)
{
    const int bx = blockIdx.x, strip = blockIdx.y;
    const int tid  = threadIdx.x;
    const int wave = tid >> 6, lane = tid & 63;
    const int quad = lane >> 4, ln16 = lane & 15;
    const int rowbase = bx * 128 + wave * 32;
    const int t0 = rowbase >> 4;

    s16x8 aq[2][4];
#pragma unroll
    for (int rs = 0; rs < 2; rs++)
#pragma unroll
        for (int kc = 0; kc < 4; kc++)
            aq[rs][kc] = ld8(Qf + ((size_t)((t0 + rs) * 4 + kc) * 64 + lane) * 8);

    float lp[8] = {0.f, 0.f, 0.f, 0.f, 0.f, 0.f, 0.f, 0.f};

    for (int it = 0; it < 4; it++) {
        const int cb = strip * 512 + it * 128;

        int4 bmv[2][4];
#pragma unroll
        for (int rs = 0; rs < 2; rs++)
#pragma unroll
            for (int r = 0; r < 4; r++)
                bmv[rs][r] = *(const int4*)(bm + (size_t)(rowbase + rs * 16 + quad * 4 + r) * 256 + (cb >> 5));

#pragma unroll
        for (int nt = 0; nt < 8; nt++) {
            s16x8 bq[4];
#pragma unroll
            for (int kc = 0; kc < 4; kc++)
                bq[kc] = ld8(Kf + ((size_t)(((cb >> 4) + nt) * 4 + kc) * 64 + lane) * 8);
            f32x4 c0 = (f32x4){0.f, 0.f, 0.f, 0.f};
            f32x4 c1 = (f32x4){0.f, 0.f, 0.f, 0.f};
#pragma unroll
            for (int kc = 0; kc < 4; kc++) {
                c0 = __builtin_amdgcn_mfma_f32_16x16x32_bf16(aq[0][kc], bq[kc], c0, 0, 0, 0);
                c1 = __builtin_amdgcn_mfma_f32_16x16x32_bf16(aq[1][kc], bq[kc], c1, 0, 0, 0);
            }
#pragma unroll
            for (int rs = 0; rs < 2; rs++)
#pragma unroll
                for (int r = 0; r < 4; r++) {
                    const unsigned d = getdw(bmv[rs][r], nt >> 1);
                    const float cv = rs ? c1[r] : c0[r];
                    if ((d >> ((nt & 1) * 16 + ln16)) & 1u)
                        lp[rs * 4 + r] += __expf(cv);
                }
        }
    }

#pragma unroll
    for (int i = 0; i < 8; i++) {
        float v = lp[i];
        v += __shfl_xor(v, 1); v += __shfl_xor(v, 2);
        v += __shfl_xor(v, 4); v += __shfl_xor(v, 8);
        if (ln16 == 0)
            atomicAdd(&lsum[rowbase + (i >> 2) * 16 + quad * 4 + (i & 3)], v);
    }
}

// ---------------------------------------------------------------------------
// Kernel 3: recompute S, write W, fused O = W @ V.
// grid(128, 8): blockIdx.x = 64-row block (4 waves x 16 rows),
// blockIdx.y = 1024-col strip (8 iters of 128 cols).
// Per-wave LDS W tile only 16x132 -> higher occupancy than R3.
// ---------------------------------------------------------------------------
__global__ __launch_bounds__(256, 4) void attn_kernel(
    const short* __restrict__ Qf, const short* __restrict__ Kf,
    const short* __restrict__ Vf, const float* __restrict__ lsum,
    const unsigned int* __restrict__ bm,
    float* __restrict__ outO, float* __restrict__ outW)
{
    __shared__ short wlds[4][16][132];   // per-wave 16x128 W tile (bf16), 16.9 KB

    const int bx = blockIdx.x, strip = blockIdx.y;
    const int tid  = threadIdx.x;
    const int wave = tid >> 6, lane = tid & 63;
    const int quad = lane >> 4, ln16 = lane & 15;
    const int rowbase = bx * 64 + wave * 16;
    const int t0 = rowbase >> 4;

    s16x8 aq[4];
#pragma unroll
    for (int kc = 0; kc < 4; kc++)
        aq[kc] = ld8(Qf + ((size_t)(t0 * 4 + kc) * 64 + lane) * 8);

    float rl[4];
#pragma unroll
    for (int r = 0; r < 4; r++)
        rl[r] = 1.0f / lsum[rowbase + quad * 4 + r];

    f32x4 o[8];
#pragma unroll
    for (int i = 0; i < 8; i++) o[i] = (f32x4){0.f, 0.f, 0.f, 0.f};

    for (int it = 0; it < 8; it++) {
        const int cb = strip * 1024 + it * 128;

        int4 bmv[4];
#pragma unroll
        for (int r = 0; r < 4; r++)
            bmv[r] = *(const int4*)(bm + (size_t)(rowbase + quad * 4 + r) * 256 + (cb >> 5));

#pragma unroll
        for (int nt = 0; nt < 8; nt++) {
            s16x8 bq[4];
#pragma unroll
            for (int kc = 0; kc < 4; kc++)
                bq[kc] = ld8(Kf + ((size_t)(((cb >> 4) + nt) * 4 + kc) * 64 + lane) * 8);
            f32x4 c = (f32x4){0.f, 0.f, 0.f, 0.f};
#pragma unroll
            for (int kc = 0; kc < 4; kc++)
                c = __builtin_amdgcn_mfma_f32_16x16x32_bf16(aq[kc], bq[kc], c, 0, 0, 0);
#pragma unroll
            for (int r = 0; r < 4; r++) {
                const int row = rowbase + quad * 4 + r;
                const unsigned d = getdw(bmv[r], nt >> 1);
                const float wv = ((d >> ((nt & 1) * 16 + ln16)) & 1u)
                                     ? __expf(c[r]) * rl[r] : 0.0f;
                outW[(size_t)row * NEFF + cb + nt * 16 + ln16] = wv;
                wlds[wave][quad * 4 + r][nt * 16 + ln16] = f2bf(wv);
            }
        }

        // PV: A from per-wave LDS (wave-internal ordering only; DS pipe is
        // in-order per wave and the compiler inserts the lgkmcnt waits),
        // B = Vf coalesced fragment stream.
#pragma unroll
        for (int ks = 0; ks < 4; ks++) {
            const s16x8 aw = ld8(&wlds[wave][ln16][ks * 32 + quad * 8]);
#pragma unroll
            for (int nt2 = 0; nt2 < 8; nt2++) {
                const s16x8 bv = ld8(Vf + ((size_t)(((cb >> 7) * 8 + nt2) * 4 + ks) * 64 + lane) * 8);
                o[nt2] = __builtin_amdgcn_mfma_f32_16x16x32_bf16(aw, bv, o[nt2], 0, 0, 0);
            }
        }
    }

    // O strip-partials -> global atomics (outO pre-zeroed)
#pragma unroll
    for (int nt2 = 0; nt2 < 8; nt2++)
#pragma unroll
        for (int r = 0; r < 4; r++) {
            const int row = rowbase + quad * 4 + r;
            atomicAdd(&outO[(size_t)row * DOUT + nt2 * 16 + ln16], o[nt2][r]);
        }
}

// ---------------------------------------------------------------------------
extern "C" void kernel_launch(void* const* d_in, const int* in_sizes, int n_in,
                              void* d_out, int out_size, void* d_ws, size_t ws_size,
                              hipStream_t stream) {
    (void)in_sizes; (void)n_in; (void)out_size; (void)ws_size;

    const float* embc = (const float*)d_in[0];
    const float* embe = (const float*)d_in[1];
    const int*   mask = (const int*)d_in[2];
    const float* Wq = (const float*)d_in[3];
    const float* bq = (const float*)d_in[4];
    const float* Wk = (const float*)d_in[5];
    const float* bk = (const float*)d_in[6];
    const float* Wv = (const float*)d_in[7];
    const float* bv = (const float*)d_in[8];

    char* ws = (char*)d_ws;
    short* Qf = (short*)(ws);                        // 2 MB  frag-major, pre-scaled
    short* Kf = (short*)(ws + (2u << 20));           // 2 MB  frag-major
    short* Vf = (short*)(ws + (4u << 20));           // 2 MB  frag-major (PV B)
    float* lsum = (float*)(ws + (6u << 20));         // 32 KB
    unsigned int* bm = (unsigned int*)(ws + (8u << 20)); // 8 MB bitmap

    float* outO = (float*)d_out;                     // [8192,128]
    float* outW = outO + (size_t)NC * DOUT;          // [8192,8192]

    hipMemsetAsync(lsum, 0, NC * sizeof(float), stream);
    hipMemsetAsync(outO, 0, (size_t)NC * DOUT * sizeof(float), stream);

    pack_kernel<<<8192, 256, 0, stream>>>(mask, (u64*)bm);
    qkv_kernel<<<dim3(128, 3), 256, 0, stream>>>(embc, embe, Wq, bq, Wk, bk, Wv, bv,
                                                 Qf, Kf, Vf);
    stats_kernel<<<dim3(64, 16), 256, 0, stream>>>(bm, Qf, Kf, lsum);
    attn_kernel<<<dim3(128, 8), 256, 0, stream>>>(Qf, Kf, Vf, lsum, bm, outO, outW);
}